// Round 4
// baseline (282.301 us; speedup 1.0000x reference)
//
#include <hip/hip_runtime.h>
#include <math.h>

#define P_NUM   16320
#define B_NUM   32
#define NCLS    21
#define TOPK    500
#define CONF_THR 0.01f
#define NMS_THR  0.45f
#define OBJ_THR  0.01f
#define NBUCKET 2048
#define CAND_CAP 1024
#define NTHREADS 512
#define NTASK   (B_NUM * (NCLS - 1))

typedef unsigned long long u64;
typedef unsigned int u32;

struct SMemA {
    u32 hist[NBUCKET];    // 8192 B
    int csum[NTHREADS];   // 2048 B
    int gsum[64];         // 256 B
    u64 keys[CAND_CAP];   // 8192 B
};

struct SMem {
    union {
        SMemA a;
        u64 mask[TOPK][8];  // 32000 B (phase-disjoint with SMemA)
    } u;
    float4 sbox[TOPK];      // 8000 B
    float  sscore[TOPK];    // 2000 B
    float  sarea[TOPK];     // 2000 B
    int    order[TOPK];     // 2000 B
    u64    rowflag[8];      // 64 B
    int    cand_count;
    int    bstar;
    int    n_emit;
};

__global__ __launch_bounds__(NTHREADS)
void refinedet_main(const float* __restrict__ arm_loc,
                    const float* __restrict__ arm_conf,
                    const float* __restrict__ odm_loc,
                    const float* __restrict__ odm_conf,
                    const float* __restrict__ priors,
                    float* __restrict__ out) {
    __shared__ SMem sm;
    const int task = blockIdx.x;
    const int tid = threadIdx.x;

    // ---- extra blocks: zero the class-0 slabs, then exit ----
    if (task >= NTASK) {
        float* o = out + (size_t)(task - NTASK) * NCLS * TOPK * 5;
        for (int f = tid; f < TOPK * 5; f += NTHREADS) o[f] = 0.0f;
        return;
    }

    // XCD-grouped mapping: blocks with the same image b share blockIdx%8
    // (same XCD on MI355X round-robin) -> odm_conf[b] slab stays L2-local.
    const int x = task & 7;
    const int slot = task >> 3;          // 0..79
    const int b = x + 8 * (slot / 20);
    const int c = slot % 20 + 1;

    // ---- Phase 0: direct strided score loads (L2-grouped), to registers ----
    const float* armc = arm_conf + (size_t)b * P_NUM * 2;
    const float* odmc = odm_conf + (size_t)b * P_NUM * NCLS;
    float s[32];
    #pragma unroll 4
    for (int k = 0; k < 32; ++k) {
        int p = tid + 512 * k;
        float sc = 0.0f;
        if (p < P_NUM) {
            float o = armc[p * 2 + 1];
            float v = odmc[p * NCLS + c];
            sc = (o > OBJ_THR) ? v : 0.0f;
        }
        s[k] = sc;
    }
    for (int i = tid; i < NBUCKET; i += NTHREADS) sm.u.a.hist[i] = 0u;
    if (tid == 0) sm.cand_count = 0;
    __syncthreads();

    // ---- Phase 1: histogram from registers ----
    #pragma unroll 4
    for (int k = 0; k < 32; ++k) {
        float sc = s[k];
        if (sc > CONF_THR) {
            int bk = (int)(sc * (float)NBUCKET);
            if (bk > NBUCKET - 1) bk = NBUCKET - 1;
            atomicAdd(&sm.u.a.hist[bk], 1u);
        }
    }
    __syncthreads();

    // ---- Phase 2: threshold bucket b* (two-level scan) ----
    {
        int s4 = 0;
        #pragma unroll
        for (int q = 0; q < 4; ++q) s4 += (int)sm.u.a.hist[tid * 4 + q];
        sm.u.a.csum[tid] = s4;
    }
    __syncthreads();
    if (tid < 64) {
        int g = 0;
        #pragma unroll
        for (int q = 0; q < 8; ++q) g += sm.u.a.csum[tid * 8 + q];
        sm.u.a.gsum[tid] = g;
    }
    __syncthreads();
    if (tid == 0) {
        int cum = 0, bstar = 0;
        for (int gg = 63; gg >= 0; --gg) {
            int gs = sm.u.a.gsum[gg];
            if (cum + gs >= TOPK) {
                for (int t = gg * 8 + 7; t >= gg * 8; --t) {
                    int cs = sm.u.a.csum[t];
                    if (cum + cs >= TOPK) {
                        for (int bk = t * 4 + 3; bk >= t * 4; --bk) {
                            cum += (int)sm.u.a.hist[bk];
                            if (cum >= TOPK) { bstar = bk; goto found; }
                        }
                    }
                    cum += cs;
                }
            }
            cum += gs;
        }
found:
        sm.bstar = bstar;   // total < 500 -> stays 0 -> gather all valid
    }
    __syncthreads();
    const int bstar = sm.bstar;

    // ---- Phase 3: gather candidates from registers ----
    #pragma unroll 4
    for (int k = 0; k < 32; ++k) {
        float sc = s[k];
        if (sc > CONF_THR) {
            int bk = (int)(sc * (float)NBUCKET);
            if (bk > NBUCKET - 1) bk = NBUCKET - 1;
            if (bk >= bstar) {
                int p = tid + 512 * k;
                int pos = atomicAdd(&sm.cand_count, 1);
                if (pos < CAND_CAP) {
                    u64 key = ((u64)__float_as_uint(sc) << 32) | (u32)(~(u32)p);
                    sm.u.a.keys[pos] = key;
                }
            }
        }
    }
    __syncthreads();
    int M = sm.cand_count; if (M > CAND_CAP) M = CAND_CAP;
    const int S = (M <= 512) ? 512 : CAND_CAP;   // common case: M ~ 505
    for (int i = M + tid; i < S; i += NTHREADS) sm.u.a.keys[i] = 0ull;
    __syncthreads();

    // ---- Phase 4: bitonic sort S keys, descending ----
    for (int k = 2; k <= S; k <<= 1) {
        for (int j = k >> 1; j > 0; j >>= 1) {
            for (int t = tid; t < S; t += NTHREADS) {
                int ixj = t ^ j;
                if (ixj > t) {
                    u64 a = sm.u.a.keys[t];
                    u64 bb = sm.u.a.keys[ixj];
                    bool desc = ((t & k) == 0);
                    if (desc ? (a < bb) : (a > bb)) {
                        sm.u.a.keys[t] = bb;
                        sm.u.a.keys[ixj] = a;
                    }
                }
            }
            __syncthreads();
        }
    }
    const int N = (M < TOPK) ? M : TOPK;

    // ---- Phase 5: cascaded decode for top-N (exact ref FP: no FMA, CR exp) ----
    for (int i = tid; i < TOPK; i += NTHREADS) {
        if (i < N) {
            u64 key = sm.u.a.keys[i];
            float sc = __uint_as_float((u32)(key >> 32));
            int p = (int)(~(u32)(key & 0xFFFFFFFFull));
            float4 pr = ((const float4*)priors)[p];
            float4 al = ((const float4*)(arm_loc + (size_t)b * P_NUM * 4))[p];
            float4 ol = ((const float4*)(odm_loc + (size_t)b * P_NUM * 4))[p];
            float cx = __fadd_rn(pr.x, __fmul_rn(__fmul_rn(al.x, 0.1f), pr.z));
            float cy = __fadd_rn(pr.y, __fmul_rn(__fmul_rn(al.y, 0.1f), pr.w));
            float w  = __fmul_rn(pr.z, (float)exp((double)__fmul_rn(al.z, 0.2f)));
            float h  = __fmul_rn(pr.w, (float)exp((double)__fmul_rn(al.w, 0.2f)));
            float mnx = __fsub_rn(cx, __fmul_rn(w, 0.5f));
            float mny = __fsub_rn(cy, __fmul_rn(h, 0.5f));
            float mxx = __fadd_rn(mnx, w);
            float mxy = __fadd_rn(mny, h);
            float dcx = __fmul_rn(__fadd_rn(mxx, mnx), 0.5f);
            float dcy = __fmul_rn(__fadd_rn(mxy, mny), 0.5f);
            float dw  = __fsub_rn(mxx, mnx);
            float dh  = __fsub_rn(mxy, mny);
            float cx2 = __fadd_rn(dcx, __fmul_rn(__fmul_rn(ol.x, 0.1f), dw));
            float cy2 = __fadd_rn(dcy, __fmul_rn(__fmul_rn(ol.y, 0.1f), dh));
            float w2  = __fmul_rn(dw, (float)exp((double)__fmul_rn(ol.z, 0.2f)));
            float h2  = __fmul_rn(dh, (float)exp((double)__fmul_rn(ol.w, 0.2f)));
            float x1 = __fsub_rn(cx2, __fmul_rn(w2, 0.5f));
            float y1 = __fsub_rn(cy2, __fmul_rn(h2, 0.5f));
            float x2 = __fadd_rn(x1, w2);
            float y2 = __fadd_rn(y1, h2);
            sm.sbox[i] = make_float4(x1, y1, x2, y2);
            sm.sscore[i] = sc;
            sm.sarea[i] = __fmul_rn(__fsub_rn(x2, x1), __fsub_rn(y2, y1));
        } else {
            sm.sbox[i] = make_float4(0.f, 0.f, 0.f, 0.f);
            sm.sscore[i] = 0.0f;
            sm.sarea[i] = 0.0f;
        }
    }
    __syncthreads();   // keys (union) dead; mask region live

    // ---- Phase 6: suppression bitmask, uniform-j broadcast scheme ----
    // One row per thread; wave w owns row-block perm{0,1,2,3,7,6,5,4}[w] so
    // SIMD s gets waves (s, s+4) with balanced j-step totals (552 each).
    // j is wave-uniform -> sbox[j]/sarea[j] are LDS broadcasts (no gather).
    {
        const int wv = tid >> 6;
        const int lane = tid & 63;
        const int rb = (wv < 4) ? wv : (11 - wv);   // 4->7,5->6,6->5,7->4
        const int i = rb * 64 + lane;               // my row (could be >= 500)
        const bool rowvalid = (i < N) && (i < TOPK);
        float4 bi; float ai;
        if (rowvalid) { bi = sm.sbox[i]; ai = sm.sarea[i]; }
        else { bi = make_float4(2.0f, 2.0f, -2.0f, -2.0f); ai = 0.0f; }
        u64 bits = 0ull, anyb = 0ull;
        int w = rb;
        for (int j = rb * 64 + 1; j < N; ++j) {
            float4 bj = sm.sbox[j];                 // broadcast
            float aj = sm.sarea[j];                 // broadcast
            float xx1 = fmaxf(bj.x, bi.x);
            float yy1 = fmaxf(bj.y, bi.y);
            float xx2 = fminf(bj.z, bi.z);
            float yy2 = fminf(bj.w, bi.w);
            float iw = fmaxf(__fsub_rn(xx2, xx1), 0.0f);
            float ih = fmaxf(__fsub_rn(yy2, yy1), 0.0f);
            float inter = __fmul_rn(iw, ih);
            float denom = __fadd_rn(__fsub_rn(aj, inter), ai);
            float q = __fmul_rn(inter, __builtin_amdgcn_rcpf(denom));
            bool nearthr = fabsf(__fsub_rn(q, NMS_THR)) < 1e-3f;
            bool sup;
            if (__builtin_expect(__any(nearthr), 0))
                sup = (__fdiv_rn(inter, denom) > NMS_THR);  // exact ref FP
            else
                sup = (q > NMS_THR);
            if (sup && j > i) bits |= (1ull << (j & 63));
            if ((j & 63) == 63) {
                if (rowvalid) sm.u.mask[i][w] = bits;
                anyb |= bits; bits = 0ull; ++w;
            }
        }
        if (rowvalid && w < 8) sm.u.mask[i][w] = bits;
        anyb |= bits;
        u64 flag = __ballot(anyb != 0ull);
        if (lane == 0) sm.rowflag[rb] = flag;
    }
    __syncthreads();

    // ---- Phase 7: serial greedy sweep, flag-gated (static reg indices) ----
    if (tid == 0) {
        u64 cur[8], fl[8];
        #pragma unroll
        for (int w = 0; w < 8; ++w) {
            int lo = w * 64;
            u64 m;
            if (N >= lo + 64)      m = ~0ull;
            else if (N <= lo)      m = 0ull;
            else                   m = (1ull << (N - lo)) - 1ull;
            cur[w] = m;
            fl[w] = sm.rowflag[w];
        }
        int cnt = 0;
        #pragma unroll
        for (int w = 0; w < 8; ++w) {
            u64 a = cur[w];
            while (a) {
                int bpos = __ffsll((unsigned long long)a) - 1;
                a &= a - 1;
                int i = w * 64 + bpos;
                sm.order[cnt++] = i;
                if ((fl[w] >> bpos) & 1ull) {
                    a &= ~sm.u.mask[i][w];
                    #pragma unroll
                    for (int ww = w + 1; ww < 8; ++ww)
                        cur[ww] &= ~sm.u.mask[i][ww];
                }
            }
        }
        sm.n_emit = cnt;
    }
    __syncthreads();

    // ---- Phase 8: write full [500,5] slab (zeros beyond cnt) ----
    float* o = out + ((size_t)(b * NCLS + c)) * TOPK * 5;
    const int cnt = sm.n_emit;
    for (int f = tid; f < TOPK * 5; f += NTHREADS) {
        int k = f / 5;
        int r = f - k * 5;
        float val = 0.0f;
        if (k < cnt) {
            int i = sm.order[k];
            float4 bx = sm.sbox[i];
            val = (r == 0) ? sm.sscore[i]
                : (r == 1) ? bx.x
                : (r == 2) ? bx.y
                : (r == 3) ? bx.z
                :            bx.w;
        }
        o[f] = val;
    }
}

extern "C" void kernel_launch(void* const* d_in, const int* in_sizes, int n_in,
                              void* d_out, int out_size, void* d_ws, size_t ws_size,
                              hipStream_t stream) {
    const float* arm_loc  = (const float*)d_in[0];
    const float* arm_conf = (const float*)d_in[1];
    const float* odm_loc  = (const float*)d_in[2];
    const float* odm_conf = (const float*)d_in[3];
    const float* priors   = (const float*)d_in[4];
    float* out = (float*)d_out;

    const int grid = NTASK + B_NUM;   // 640 tasks + 32 class-0 zeroers
    refinedet_main<<<grid, NTHREADS, 0, stream>>>(
        arm_loc, arm_conf, odm_loc, odm_conf, priors, out);
}

// Round 5
// 239.755 us; speedup vs baseline: 1.1775x; 1.1775x over previous
//
#include <hip/hip_runtime.h>
#include <math.h>

#define P_NUM   16320
#define B_NUM   32
#define NCLS    21
#define TOPK    500
#define CONF_THR 0.01f
#define NMS_THR  0.45f
#define OBJ_THR  0.01f
#define NBUCKET 2048
#define CAND_CAP 1024
#define NTHREADS 512
#define CHUNK   256
#define NTASK   (B_NUM * (NCLS - 1))

typedef unsigned long long u64;
typedef unsigned int u32;

struct SMemA {
    u32 hist[NBUCKET];    // 8192 B
    int csum[NTHREADS];   // 2048 B
    int gsum[64];         // 256 B
    u64 keys[CAND_CAP];   // 8192 B  (also cross-wave sort exchange buffer)
};

struct SMem {
    union {
        SMemA a;
        u64 mask[TOPK][8];  // 32000 B (phase-disjoint with SMemA)
    } u;
    float4 sbox[TOPK];      // 8000 B
    float  sscore[TOPK];    // 2000 B
    float  sarea[TOPK];     // 2000 B
    int    order[TOPK];     // 2000 B
    u64    rowflag[8];      // 64 B
    u64    alive[8];        // 64 B
    int    wordpref[8];     // 32 B
    int    cand_count;
    int    bstar;
    int    n_emit;
};

// ---- mask + transpose odm_conf into per-task contiguous score arrays ----
__global__ __launch_bounds__(256)
void mask_transpose(const float* __restrict__ arm_conf,
                    const float* __restrict__ odm_conf,
                    float* __restrict__ ws) {
    __shared__ float tile[NCLS][CHUNK + 1];
    __shared__ float obj[CHUNK];
    const int blk = blockIdx.x;
    const int b = blk >> 6;
    const int ch = blk & 63;
    const int p0 = ch * CHUNK;
    const int np = min(CHUNK, P_NUM - p0);    // 256, last chunk 192
    const int tid = threadIdx.x;

    const float4* oc4 = (const float4*)(odm_conf + ((size_t)b * P_NUM + p0) * NCLS);
    const float* ac = arm_conf + ((size_t)b * P_NUM + p0) * 2;
    const int count4 = (np * NCLS) / 4;       // 1344 or 1008
    for (int q = tid; q < count4; q += 256) {
        float4 v = oc4[q];                    // coalesced 16B
        int f = 4 * q;
        {
            int p = f / NCLS;       int cc = f - p * NCLS;       tile[cc][p] = v.x;
        }
        {
            int p = (f+1) / NCLS;   int cc = (f+1) - p * NCLS;   tile[cc][p] = v.y;
        }
        {
            int p = (f+2) / NCLS;   int cc = (f+2) - p * NCLS;   tile[cc][p] = v.z;
        }
        {
            int p = (f+3) / NCLS;   int cc = (f+3) - p * NCLS;   tile[cc][p] = v.w;
        }
    }
    if (tid < np) obj[tid] = ac[tid * 2 + 1];
    __syncthreads();

    const int nv = np / 4;                    // 64 or 48
    const int total = 20 * nv;
    for (int i = tid; i < total; i += 256) {
        int cc = i / nv;                      // 0..19 -> class cc+1
        int pp = i - cc * nv;
        const float* t = &tile[cc + 1][4 * pp];
        float4 ov = make_float4(
            (obj[4*pp+0] > OBJ_THR) ? t[0] : 0.0f,
            (obj[4*pp+1] > OBJ_THR) ? t[1] : 0.0f,
            (obj[4*pp+2] > OBJ_THR) ? t[2] : 0.0f,
            (obj[4*pp+3] > OBJ_THR) ? t[3] : 0.0f);
        float4* w4 = (float4*)(ws + ((size_t)(b * 20 + cc)) * P_NUM + p0);
        w4[pp] = ov;                          // coalesced 16B store
    }
}

template <bool PACKED>
__global__ __launch_bounds__(NTHREADS)
void refinedet_main(const float* __restrict__ arm_loc,
                    const float* __restrict__ arm_conf,
                    const float* __restrict__ odm_loc,
                    const float* __restrict__ odm_conf,
                    const float* __restrict__ priors,
                    const float* __restrict__ ws_scores,
                    float* __restrict__ out) {
    __shared__ SMem sm;
    const int task = blockIdx.x;
    const int tid = threadIdx.x;

    // ---- extra blocks: zero the class-0 slabs, then exit ----
    if (task >= NTASK) {
        float* o = out + (size_t)(task - NTASK) * NCLS * TOPK * 5;
        for (int f = tid; f < TOPK * 5; f += NTHREADS) o[f] = 0.0f;
        return;
    }

    const int b = task / (NCLS - 1);
    const int c = task % (NCLS - 1) + 1;

    // ---- Phase 0: load my 32 scores into registers (single global pass) ----
    float s[32];
    if (PACKED) {
        const float4* sp = (const float4*)(ws_scores + (size_t)task * P_NUM);
        #pragma unroll
        for (int v = 0; v < 8; ++v) {
            int q = tid + 512 * v;            // 4080 float4s total
            float4 val = (q < 4080) ? sp[q] : make_float4(0.f, 0.f, 0.f, 0.f);
            s[4 * v + 0] = val.x; s[4 * v + 1] = val.y;
            s[4 * v + 2] = val.z; s[4 * v + 3] = val.w;
        }
    } else {
        const float* armc = arm_conf + (size_t)b * P_NUM * 2;
        const float* odmc = odm_conf + (size_t)b * P_NUM * NCLS;
        #pragma unroll 4
        for (int k = 0; k < 32; ++k) {
            int p = tid + 512 * k;
            float sc = 0.0f;
            if (p < P_NUM) {
                float o = armc[p * 2 + 1];
                sc = (o > OBJ_THR) ? odmc[p * NCLS + c] : 0.0f;
            }
            s[k] = sc;
        }
    }
    for (int i = tid; i < NBUCKET; i += NTHREADS) sm.u.a.hist[i] = 0u;
    if (tid == 0) sm.cand_count = 0;
    __syncthreads();

    // ---- Phase 1: histogram from registers ----
    #pragma unroll 4
    for (int k = 0; k < 32; ++k) {
        float sc = s[k];
        if (sc > CONF_THR) {
            int bk = (int)(sc * (float)NBUCKET);
            if (bk > NBUCKET - 1) bk = NBUCKET - 1;
            atomicAdd(&sm.u.a.hist[bk], 1u);
        }
    }
    __syncthreads();

    // ---- Phase 2: threshold bucket b* (two-level scan) ----
    {
        int s4 = 0;
        #pragma unroll
        for (int q = 0; q < 4; ++q) s4 += (int)sm.u.a.hist[tid * 4 + q];
        sm.u.a.csum[tid] = s4;
    }
    __syncthreads();
    if (tid < 64) {
        int g = 0;
        #pragma unroll
        for (int q = 0; q < 8; ++q) g += sm.u.a.csum[tid * 8 + q];
        sm.u.a.gsum[tid] = g;
    }
    __syncthreads();
    if (tid == 0) {
        int cum = 0, bstar = 0;
        for (int gg = 63; gg >= 0; --gg) {
            int gs = sm.u.a.gsum[gg];
            if (cum + gs >= TOPK) {
                for (int t = gg * 8 + 7; t >= gg * 8; --t) {
                    int cs = sm.u.a.csum[t];
                    if (cum + cs >= TOPK) {
                        for (int bk = t * 4 + 3; bk >= t * 4; --bk) {
                            cum += (int)sm.u.a.hist[bk];
                            if (cum >= TOPK) { bstar = bk; goto found; }
                        }
                    }
                    cum += cs;
                }
            }
            cum += gs;
        }
found:
        sm.bstar = bstar;   // total < 500 -> stays 0 -> gather all valid
    }
    __syncthreads();
    const int bstar = sm.bstar;

    // ---- Phase 3: gather candidates from registers ----
    #pragma unroll 4
    for (int k = 0; k < 32; ++k) {
        float sc = s[k];
        if (sc > CONF_THR) {
            int bk = (int)(sc * (float)NBUCKET);
            if (bk > NBUCKET - 1) bk = NBUCKET - 1;
            if (bk >= bstar) {
                int p;
                if (PACKED) p = 4 * (tid + 512 * (k >> 2)) + (k & 3);
                else        p = tid + 512 * k;
                int pos = atomicAdd(&sm.cand_count, 1);
                if (pos < CAND_CAP) {
                    u64 key = ((u64)__float_as_uint(sc) << 32) | (u32)(~(u32)p);
                    sm.u.a.keys[pos] = key;
                }
            }
        }
    }
    __syncthreads();
    int M = sm.cand_count; if (M > CAND_CAP) M = CAND_CAP;

    // ---- Phase 4: sort descending; common path = register bitonic (512) ----
    u64 v;
    if (__builtin_expect(M <= 512, 1)) {
        for (int i = M + tid; i < 512; i += NTHREADS) sm.u.a.keys[i] = 0ull;
        __syncthreads();
        v = sm.u.a.keys[tid];
        #pragma unroll
        for (int k = 2; k <= 512; k <<= 1) {
            for (int j = k >> 1; j > 0; j >>= 1) {
                u64 p;
                if (j >= 64) {                 // cross-wave: LDS exchange
                    sm.u.a.keys[tid] = v;
                    __syncthreads();
                    p = sm.u.a.keys[tid ^ j];
                    __syncthreads();
                } else {                        // in-wave: register shuffle
                    p = __shfl_xor((unsigned long long)v, j, 64);
                }
                const bool desc = ((tid & k) == 0);
                const bool lower = ((tid & j) == 0);
                const bool takeMax = (desc == lower);
                v = (takeMax == (v < p)) ? p : v;
            }
        }
    } else {
        // rare fallback: LDS bitonic on 1024
        for (int i = M + tid; i < CAND_CAP; i += NTHREADS) sm.u.a.keys[i] = 0ull;
        __syncthreads();
        for (int k = 2; k <= CAND_CAP; k <<= 1) {
            for (int j = k >> 1; j > 0; j >>= 1) {
                for (int t = tid; t < CAND_CAP; t += NTHREADS) {
                    int ixj = t ^ j;
                    if (ixj > t) {
                        u64 a = sm.u.a.keys[t];
                        u64 bb = sm.u.a.keys[ixj];
                        bool desc = ((t & k) == 0);
                        if (desc ? (a < bb) : (a > bb)) {
                            sm.u.a.keys[t] = bb;
                            sm.u.a.keys[ixj] = a;
                        }
                    }
                }
                __syncthreads();
            }
        }
        v = sm.u.a.keys[tid];
    }
    const int N = (M < TOPK) ? M : TOPK;

    // ---- Phase 5: cascaded decode, one row per thread from register key ----
    if (tid < 8) sm.rowflag[tid] = 0ull;
    if (tid < N) {
        float sc = __uint_as_float((u32)(v >> 32));
        int p = (int)(~(u32)(v & 0xFFFFFFFFull));
        float4 pr = ((const float4*)priors)[p];
        float4 al = ((const float4*)(arm_loc + (size_t)b * P_NUM * 4))[p];
        float4 ol = ((const float4*)(odm_loc + (size_t)b * P_NUM * 4))[p];
        float cx = __fadd_rn(pr.x, __fmul_rn(__fmul_rn(al.x, 0.1f), pr.z));
        float cy = __fadd_rn(pr.y, __fmul_rn(__fmul_rn(al.y, 0.1f), pr.w));
        float w  = __fmul_rn(pr.z, (float)exp((double)__fmul_rn(al.z, 0.2f)));
        float h  = __fmul_rn(pr.w, (float)exp((double)__fmul_rn(al.w, 0.2f)));
        float mnx = __fsub_rn(cx, __fmul_rn(w, 0.5f));
        float mny = __fsub_rn(cy, __fmul_rn(h, 0.5f));
        float mxx = __fadd_rn(mnx, w);
        float mxy = __fadd_rn(mny, h);
        float dcx = __fmul_rn(__fadd_rn(mxx, mnx), 0.5f);
        float dcy = __fmul_rn(__fadd_rn(mxy, mny), 0.5f);
        float dw  = __fsub_rn(mxx, mnx);
        float dh  = __fsub_rn(mxy, mny);
        float cx2 = __fadd_rn(dcx, __fmul_rn(__fmul_rn(ol.x, 0.1f), dw));
        float cy2 = __fadd_rn(dcy, __fmul_rn(__fmul_rn(ol.y, 0.1f), dh));
        float w2  = __fmul_rn(dw, (float)exp((double)__fmul_rn(ol.z, 0.2f)));
        float h2  = __fmul_rn(dh, (float)exp((double)__fmul_rn(ol.w, 0.2f)));
        float x1 = __fsub_rn(cx2, __fmul_rn(w2, 0.5f));
        float y1 = __fsub_rn(cy2, __fmul_rn(h2, 0.5f));
        float x2 = __fadd_rn(x1, w2);
        float y2 = __fadd_rn(y1, h2);
        sm.sbox[tid] = make_float4(x1, y1, x2, y2);
        sm.sscore[tid] = sc;
        sm.sarea[tid] = __fmul_rn(__fsub_rn(x2, x1), __fsub_rn(y2, y1));
    }
    __syncthreads();   // keys (union) dead; mask region live; rowflag zeroed

    // ---- Phase 6: suppression bitmask, uniform-j broadcast scheme ----
    // One row per thread; wave w owns row-block perm{0,1,2,3,7,6,5,4}[w] so
    // each SIMD gets balanced j-step totals. j is wave-uniform -> LDS broadcast.
    {
        const int wv = tid >> 6;
        const int lane = tid & 63;
        const int rb = (wv < 4) ? wv : (11 - wv);
        const int i = rb * 64 + lane;
        const bool rowvalid = (i < N) && (i < TOPK);
        float4 bi; float ai;
        if (rowvalid) { bi = sm.sbox[i]; ai = sm.sarea[i]; }
        else { bi = make_float4(2.0f, 2.0f, -2.0f, -2.0f); ai = 0.0f; }
        u64 bits = 0ull, anyb = 0ull;
        int w = rb;
        for (int j = rb * 64 + 1; j < N; ++j) {
            float4 bj = sm.sbox[j];                 // broadcast
            float aj = sm.sarea[j];                 // broadcast
            float xx1 = fmaxf(bj.x, bi.x);
            float yy1 = fmaxf(bj.y, bi.y);
            float xx2 = fminf(bj.z, bi.z);
            float yy2 = fminf(bj.w, bi.w);
            float iw = fmaxf(__fsub_rn(xx2, xx1), 0.0f);
            float ih = fmaxf(__fsub_rn(yy2, yy1), 0.0f);
            float inter = __fmul_rn(iw, ih);
            float denom = __fadd_rn(__fsub_rn(aj, inter), ai);
            float q = __fmul_rn(inter, __builtin_amdgcn_rcpf(denom));
            bool nearthr = fabsf(__fsub_rn(q, NMS_THR)) < 1e-3f;
            bool sup;
            if (__builtin_expect(__any(nearthr), 0))
                sup = (__fdiv_rn(inter, denom) > NMS_THR);  // exact ref FP
            else
                sup = (q > NMS_THR);
            if (sup && j > i) bits |= (1ull << (j & 63));
            if ((j & 63) == 63) {
                if (rowvalid) sm.u.mask[i][w] = bits;
                anyb |= bits; bits = 0ull; ++w;
            }
        }
        if (rowvalid && w < 8) sm.u.mask[i][w] = bits;
        anyb |= bits;
        u64 flag = __ballot(anyb != 0ull);
        if (lane == 0) sm.rowflag[rb] = flag;
    }
    __syncthreads();

    // ---- Phase 7: greedy sweep — serial over flagged rows only, then
    //      parallel popcount-prefix compaction of survivors ----
    if (tid == 0) {
        u64 cur[8];
        #pragma unroll
        for (int w = 0; w < 8; ++w) {
            int lo = w * 64;
            cur[w] = (N >= lo + 64) ? ~0ull
                   : (N <= lo)      ? 0ull
                   : ((1ull << (N - lo)) - 1ull);
        }
        // mask[i] holds only bits j>i, so applying flagged rows in ascending
        // order (alive-checked) reproduces the full greedy sweep exactly.
        #pragma unroll
        for (int w = 0; w < 8; ++w) {
            u64 f = sm.rowflag[w];
            while (f) {
                int bpos = __ffsll((unsigned long long)f) - 1;
                f &= f - 1;
                if ((cur[w] >> bpos) & 1ull) {
                    int i = w * 64 + bpos;
                    cur[w] &= ~sm.u.mask[i][w];
                    #pragma unroll
                    for (int ww = w + 1; ww < 8; ++ww)
                        cur[ww] &= ~sm.u.mask[i][ww];
                }
            }
        }
        int pref = 0;
        #pragma unroll
        for (int w = 0; w < 8; ++w) {
            sm.alive[w] = cur[w];
            sm.wordpref[w] = pref;
            pref += __popcll(cur[w]);
        }
        sm.n_emit = pref;
    }
    __syncthreads();
    if (tid < TOPK) {
        int w = tid >> 6, bpos = tid & 63;
        u64 aw = sm.alive[w];
        if ((aw >> bpos) & 1ull) {
            int pos = sm.wordpref[w] + __popcll(aw & ((1ull << bpos) - 1ull));
            sm.order[pos] = tid;
        }
    }
    __syncthreads();

    // ---- Phase 8: write full [500,5] slab (zeros beyond cnt) ----
    float* o = out + ((size_t)(b * NCLS + c)) * TOPK * 5;
    const int cnt = sm.n_emit;
    for (int f = tid; f < TOPK * 5; f += NTHREADS) {
        int k = f / 5;
        int r = f - k * 5;
        float val = 0.0f;
        if (k < cnt) {
            int i = sm.order[k];
            float4 bx = sm.sbox[i];
            val = (r == 0) ? sm.sscore[i]
                : (r == 1) ? bx.x
                : (r == 2) ? bx.y
                : (r == 3) ? bx.z
                :            bx.w;
        }
        o[f] = val;
    }
}

extern "C" void kernel_launch(void* const* d_in, const int* in_sizes, int n_in,
                              void* d_out, int out_size, void* d_ws, size_t ws_size,
                              hipStream_t stream) {
    const float* arm_loc  = (const float*)d_in[0];
    const float* arm_conf = (const float*)d_in[1];
    const float* odm_loc  = (const float*)d_in[2];
    const float* odm_conf = (const float*)d_in[3];
    const float* priors   = (const float*)d_in[4];
    float* out = (float*)d_out;

    const int grid = NTASK + B_NUM;   // 640 tasks + 32 class-0 zeroers
    const size_t need = (size_t)NTASK * P_NUM * sizeof(float); // 41.8 MB
    if (ws_size >= need) {
        float* wsf = (float*)d_ws;
        mask_transpose<<<B_NUM * 64, 256, 0, stream>>>(arm_conf, odm_conf, wsf);
        refinedet_main<true><<<grid, NTHREADS, 0, stream>>>(
            arm_loc, arm_conf, odm_loc, odm_conf, priors, wsf, out);
    } else {
        refinedet_main<false><<<grid, NTHREADS, 0, stream>>>(
            arm_loc, arm_conf, odm_loc, odm_conf, priors, nullptr, out);
    }
}